// Round 1
// baseline (802.724 us; speedup 1.0000x reference)
//
#include <hip/hip_runtime.h>
#include <hip/hip_bf16.h>
#include <math.h>

__device__ __forceinline__ float geluf(float x) {
    return 0.5f * x * (1.0f + erff(x * 0.70710678118654752f));
}

__device__ __forceinline__ float wave_reduce_sum(float v) {
    #pragma unroll
    for (int m = 32; m >= 1; m >>= 1) v += __shfl_xor(v, m, 64);
    return v;
}

// --- Kernel 1: node_features = LN(ent + role_emb[roles]) over E=768, one wave per row
__global__ __launch_bounds__(256) void nf_ln_kernel(
    const float* __restrict__ ent, const int* __restrict__ roles,
    const float* __restrict__ role_emb, const float* __restrict__ g,
    const float* __restrict__ bta, float* __restrict__ nf)
{
    int wave = threadIdx.x >> 6, lane = threadIdx.x & 63;
    int row = blockIdx.x * 4 + wave;            // 0..8191
    const float* er = ent + (size_t)row * 768;
    const float* rr = role_emb + roles[row] * 768;
    float x[12]; float s = 0.f, s2 = 0.f;
    #pragma unroll
    for (int i = 0; i < 12; ++i) {
        x[i] = er[i * 64 + lane] + rr[i * 64 + lane];
        s += x[i]; s2 += x[i] * x[i];
    }
    s = wave_reduce_sum(s); s2 = wave_reduce_sum(s2);
    float mu = s * (1.f / 768.f);
    float var = s2 * (1.f / 768.f) - mu * mu;
    float rs = rsqrtf(var + 1e-5f);
    float* outp = nf + (size_t)row * 768;
    #pragma unroll
    for (int i = 0; i < 12; ++i) {
        int c = i * 64 + lane;
        outp[c] = (x[i] - mu) * rs * g[c] + bta[c];
    }
}

// --- Kernel 2: q = gelu(q_emb @ Wq + bq), [64,768]x[768,1024]
__global__ __launch_bounds__(256) void q_kernel(
    const float* __restrict__ q_emb, const float* __restrict__ Wq,
    const float* __restrict__ bq, float* __restrict__ qout)
{
    __shared__ float sq[768];
    int b = blockIdx.y;
    int col = blockIdx.x * 256 + threadIdx.x;
    for (int i = threadIdx.x; i < 768; i += 256) sq[i] = q_emb[b * 768 + i];
    __syncthreads();
    float acc = 0.f;
    #pragma unroll 4
    for (int k = 0; k < 768; ++k) acc = fmaf(sq[k], Wq[(size_t)k * 1024 + col], acc);
    qout[b * 1024 + col] = geluf(acc + bq[col]);
}

// --- Tiled fp32 GEMM with gelu(x+bias) epilogue.
// MODE 0: A from memory. MODE 1: A = interaction row built from qbuf/kbuf.
// Tile 128x128x32, 256 threads, 8x8 micro-tile per thread.
template<int MODE>
__global__ __launch_bounds__(256) void gemm_gelu_kernel(
    const float* __restrict__ A, const float* __restrict__ B,
    const float* __restrict__ bias, float* __restrict__ C,
    int M, int N, int K,
    const float* __restrict__ qbuf, const float* __restrict__ kbuf)
{
    __shared__ float As[32][132];   // [k][m], +4 pad: b128-aligned rows, low-conflict
    __shared__ float Bs[32][132];   // [k][n]
    const int tid = threadIdx.x;
    const int bm = blockIdx.y * 128;
    const int bn = blockIdx.x * 128;
    const int tx = tid & 15;
    const int ty = tid >> 4;
    float acc[8][8];
    #pragma unroll
    for (int i = 0; i < 8; ++i)
        #pragma unroll
        for (int j = 0; j < 8; ++j) acc[i][j] = 0.f;

    const int ka = tid & 31;   // k within tile for A staging
    const int ra = tid >> 5;   // 0..7
    const int cb = tid & 127;  // col for B staging
    const int kb = tid >> 7;   // 0..1

    for (int k0 = 0; k0 < K; k0 += 32) {
        #pragma unroll
        for (int p = 0; p < 16; ++p) {
            int row = ra + p * 8;
            int gr = bm + row;
            int gk = k0 + ka;
            float v;
            if (MODE == 0) {
                v = A[(size_t)gr * K + gk];
            } else {
                // gr = (b*128+n)*8 + h ; gk = 128*blk + d
                int h = gr & 7;
                int d = gk & 127;
                int blk = gk >> 7;
                float qv = qbuf[(gr >> 10) * 1024 + h * 128 + d];
                float kv = kbuf[(size_t)(gr >> 3) * 1024 + h * 128 + d];
                v = (blk == 0) ? qv : (blk == 1) ? kv
                  : (blk == 2) ? fabsf(qv - kv) : qv * kv;
            }
            As[ka][row] = v;
        }
        #pragma unroll
        for (int p = 0; p < 16; ++p) {
            int kr = kb + p * 2;
            Bs[kr][cb] = B[(size_t)(k0 + kr) * N + bn + cb];
        }
        __syncthreads();
        #pragma unroll 8
        for (int k = 0; k < 32; ++k) {
            float a[8], bb[8];
            #pragma unroll
            for (int i = 0; i < 8; ++i) a[i] = As[k][ty * 8 + i];
            #pragma unroll
            for (int j = 0; j < 8; ++j) bb[j] = Bs[k][tx * 8 + j];
            #pragma unroll
            for (int i = 0; i < 8; ++i)
                #pragma unroll
                for (int j = 0; j < 8; ++j)
                    acc[i][j] = fmaf(a[i], bb[j], acc[i][j]);
        }
        __syncthreads();
    }
    #pragma unroll
    for (int i = 0; i < 8; ++i) {
        int gr = bm + ty * 8 + i;
        float o[8];
        #pragma unroll
        for (int j = 0; j < 8; ++j) {
            int gc = bn + tx * 8 + j;
            o[j] = geluf(acc[i][j] + bias[gc]);
        }
        float4* dst = (float4*)&C[(size_t)gr * N + bn + tx * 8];
        dst[0] = make_float4(o[0], o[1], o[2], o[3]);
        dst[1] = make_float4(o[4], o[5], o[6], o[7]);
    }
}

// --- In-place row LayerNorm, one wave per row, W = 256 or 128
template<int W>
__global__ __launch_bounds__(256) void ln_kernel(
    float* __restrict__ buf, const float* __restrict__ g, const float* __restrict__ bta)
{
    constexpr int E = W / 64;
    int wave = threadIdx.x >> 6, lane = threadIdx.x & 63;
    int row = blockIdx.x * 4 + wave;
    float* p = buf + (size_t)row * W;
    float x[E]; float s = 0.f, s2 = 0.f;
    #pragma unroll
    for (int i = 0; i < E; ++i) {
        x[i] = p[i * 64 + lane];
        s += x[i]; s2 += x[i] * x[i];
    }
    s = wave_reduce_sum(s); s2 = wave_reduce_sum(s2);
    float mu = s * (1.f / W);
    float var = s2 * (1.f / W) - mu * mu;
    float rs = rsqrtf(var + 1e-5f);
    #pragma unroll
    for (int i = 0; i < E; ++i) {
        int c = i * 64 + lane;
        p[c] = (x[i] - mu) * rs * g[c] + bta[c];
    }
}

// --- scores[row] = dot(h2[row,:128], W3) + b3, one wave per row
__global__ __launch_bounds__(256) void score_kernel(
    const float* __restrict__ h2, const float* __restrict__ W3,
    const float* __restrict__ b3, float* __restrict__ scores)
{
    int lane = threadIdx.x & 63;
    int row = blockIdx.x * 4 + (threadIdx.x >> 6);
    const float* p = h2 + (size_t)row * 128;
    float v = p[lane] * W3[lane] + p[64 + lane] * W3[64 + lane];
    v = wave_reduce_sum(v);
    if (lane == 0) scores[row] = v + b3[0];
}

// --- out[b] = sigmoid( sum_{n,h} score*gate*mask / 8 )
__global__ __launch_bounds__(256) void final_kernel(
    const float* __restrict__ scores, const float* __restrict__ idfs,
    const float* __restrict__ mask, const float* __restrict__ gate_w,
    const float* __restrict__ gate_b, float* __restrict__ outp)
{
    int b = blockIdx.x, tid = threadIdx.x;
    float gw = gate_w[0], gb = gate_b[0];
    float acc = 0.f;
    for (int i = tid; i < 1024; i += 256) {
        int n = i >> 3;
        float lg = log1pf(idfs[b * 128 + n]);
        float gate = 1.f / (1.f + expf(-(lg * gw + gb)));
        acc += scores[b * 1024 + i] * gate * mask[b * 128 + n];
    }
    acc = wave_reduce_sum(acc);
    __shared__ float wsum[4];
    if ((tid & 63) == 0) wsum[tid >> 6] = acc;
    __syncthreads();
    if (tid == 0) {
        float t = wsum[0] + wsum[1] + wsum[2] + wsum[3];
        outp[b] = 1.f / (1.f + expf(-t * 0.125f));
    }
}

extern "C" void kernel_launch(void* const* d_in, const int* in_sizes, int n_in,
                              void* d_out, int out_size, void* d_ws, size_t ws_size,
                              hipStream_t stream) {
    const float* q_emb    = (const float*)d_in[0];
    const float* ent      = (const float*)d_in[1];
    const int*   roles    = (const int*)d_in[2];
    const float* idfs     = (const float*)d_in[3];
    const float* mask     = (const float*)d_in[4];
    const float* role_emb = (const float*)d_in[5];
    const float* ln_f_g   = (const float*)d_in[6];
    const float* ln_f_b   = (const float*)d_in[7];
    const float* Wq       = (const float*)d_in[8];
    const float* bq       = (const float*)d_in[9];
    const float* Wk       = (const float*)d_in[10];
    const float* bk       = (const float*)d_in[11];
    const float* W1       = (const float*)d_in[12];
    const float* b1       = (const float*)d_in[13];
    const float* ln1_g    = (const float*)d_in[14];
    const float* ln1_b    = (const float*)d_in[15];
    const float* W2       = (const float*)d_in[16];
    const float* b2       = (const float*)d_in[17];
    const float* ln2_g    = (const float*)d_in[18];
    const float* ln2_b    = (const float*)d_in[19];
    const float* W3       = (const float*)d_in[20];
    const float* b3       = (const float*)d_in[21];
    const float* gate_w   = (const float*)d_in[22];
    const float* gate_b   = (const float*)d_in[23];
    float* outp = (float*)d_out;

    // workspace layout (bytes), overlapping dead live-ranges; peak ~101.2 MB
    char* ws = (char*)d_ws;
    float* qbuf   = (float*)(ws);                        // [64,1024]   0 .. 0.26MB
    float* kbuf   = (float*)(ws + (size_t)262144);       // [8192,1024] .. 33.8MB
    float* nf     = (float*)(ws + (size_t)33816576);     // [8192,768]  .. 59MB (dead after k-GEMM)
    float* h1     = (float*)(ws + (size_t)33816576);     // [65536,256] .. 100.9MB (reuses nf)
    float* h2     = (float*)(ws);                        // [65536,128] 0 .. 33.5MB (reuses q+kbuf)
    float* scores = (float*)(ws + (size_t)100925440);    // [65536]

    nf_ln_kernel<<<2048, 256, 0, stream>>>(ent, roles, role_emb, ln_f_g, ln_f_b, nf);
    q_kernel<<<dim3(4, 64), 256, 0, stream>>>(q_emb, Wq, bq, qbuf);
    // k = gelu(nf @ Wk + bk): [8192,768]x[768,1024]
    gemm_gelu_kernel<0><<<dim3(8, 64), 256, 0, stream>>>(
        nf, Wk, bk, kbuf, 8192, 1024, 768, nullptr, nullptr);
    // h1 = gelu(interaction @ W1 + b1): [65536,512]x[512,256]
    gemm_gelu_kernel<1><<<dim3(2, 512), 256, 0, stream>>>(
        nullptr, W1, b1, h1, 65536, 256, 512, qbuf, kbuf);
    ln_kernel<256><<<16384, 256, 0, stream>>>(h1, ln1_g, ln1_b);
    // h2 = gelu(h1 @ W2 + b2): [65536,256]x[256,128]
    gemm_gelu_kernel<0><<<dim3(1, 512), 256, 0, stream>>>(
        h1, W2, b2, h2, 65536, 128, 256, nullptr, nullptr);
    ln_kernel<128><<<16384, 256, 0, stream>>>(h2, ln2_g, ln2_b);
    score_kernel<<<16384, 256, 0, stream>>>(h2, W3, b3, scores);
    final_kernel<<<64, 256, 0, stream>>>(scores, idfs, mask, gate_w, gate_b, outp);
}

// Round 2
// 307.407 us; speedup vs baseline: 2.6113x; 2.6113x over previous
//
#include <hip/hip_runtime.h>
#include <hip/hip_bf16.h>
#include <math.h>

typedef unsigned short u16;
typedef short s16x8 __attribute__((ext_vector_type(8)));
typedef float f32x4 __attribute__((ext_vector_type(4)));

// k-interleave within a 32-wide k-tile: position of k so that a lane's
// contiguous 16B read = [k=4g..4g+3, k=16+4g..16+4g+3] (g = lane>>4)
__device__ __host__ __forceinline__ int KP(int k) {
    return (((k) & 12) << 1) | ((((k) >> 4) & 1) << 2) | ((k) & 3);
}

__device__ __forceinline__ float geluf(float x) {
    return 0.5f * x * (1.0f + erff(x * 0.70710678118654752f));
}
__device__ __forceinline__ u16 f2bf(float f) {
    unsigned u = __builtin_bit_cast(unsigned, f);
    return (u16)((u + 0x7fffu + ((u >> 16) & 1u)) >> 16);
}
__device__ __forceinline__ float bf2f(u16 h) {
    return __builtin_bit_cast(float, ((unsigned)h) << 16);
}
__device__ __forceinline__ void async_copy16(const u16* gsrc, u16* ldst) {
    __builtin_amdgcn_global_load_lds((const __attribute__((address_space(1))) void*)gsrc,
                                     (__attribute__((address_space(3))) void*)ldst, 16, 0, 0);
}

// ---------- prep: W[K][N] fp32 -> blocked bf16 B-tiles [CB cols][32 k], col-major rows
__global__ __launch_bounds__(256) void prep_w(const float* __restrict__ W, u16* __restrict__ out,
                                              int K, int N, int CB) {
    int idx = blockIdx.x * 256 + threadIdx.x;
    if (idx >= K * N) return;
    int k = idx / N, col = idx % N;
    int cb = col / CB, ci = col % CB, kt = k >> 5, ki = k & 31;
    size_t pos = ((size_t)(cb * (K >> 5) + kt) * CB + ci) * 32 + KP(ki);
    out[pos] = f2bf(W[idx]);
}

__device__ __forceinline__ float wave_reduce_sum(float v) {
    #pragma unroll
    for (int m = 32; m >= 1; m >>= 1) v += __shfl_xor(v, m, 64);
    return v;
}

// ---------- nf = LN(ent + role_emb[roles]) -> blocked bf16 A-tiles [128][32]
__global__ __launch_bounds__(256) void nf_ln_kernel(
    const float* __restrict__ ent, const int* __restrict__ roles,
    const float* __restrict__ role_emb, const float* __restrict__ g,
    const float* __restrict__ bta, u16* __restrict__ nfb)
{
    int wave = threadIdx.x >> 6, lane = threadIdx.x & 63;
    int row = blockIdx.x * 4 + wave;
    const float* er = ent + (size_t)row * 768;
    const float* rr = role_emb + roles[row] * 768;
    float x[12]; float s = 0.f, s2 = 0.f;
    #pragma unroll
    for (int i = 0; i < 12; ++i) {
        x[i] = er[i * 64 + lane] + rr[i * 64 + lane];
        s += x[i]; s2 += x[i] * x[i];
    }
    s = wave_reduce_sum(s); s2 = wave_reduce_sum(s2);
    float mu = s * (1.f / 768.f);
    float var = s2 * (1.f / 768.f) - mu * mu;
    float rs = rsqrtf(var + 1e-5f);
    size_t rb = (size_t)(row >> 7) * 24;
    int rin = row & 127;
    #pragma unroll
    for (int i = 0; i < 12; ++i) {
        int k = i * 64 + lane;
        float v = (x[i] - mu) * rs * g[k] + bta[k];
        size_t pos = (rb + (k >> 5)) * 4096 + (size_t)rin * 32 + KP(k & 31);
        nfb[pos] = f2bf(v);
    }
}

// ---------- q = gelu(q_emb @ Wq + bq) -> bf16 [64][1024]
__global__ __launch_bounds__(256) void q_kernel(
    const float* __restrict__ q_emb, const float* __restrict__ Wq,
    const float* __restrict__ bq, u16* __restrict__ qout)
{
    __shared__ float sq[768];
    int b = blockIdx.y;
    int col = blockIdx.x * 256 + threadIdx.x;
    for (int i = threadIdx.x; i < 768; i += 256) sq[i] = q_emb[b * 768 + i];
    __syncthreads();
    float acc = 0.f;
    #pragma unroll 4
    for (int k = 0; k < 768; ++k) acc = fmaf(sq[k], Wq[(size_t)k * 1024 + col], acc);
    qout[b * 1024 + col] = f2bf(geluf(acc + bq[col]));
}

// ---------- interaction build: [qk, k, |q-k|, q*k] -> blocked bf16 A-tiles [128][32]
__global__ __launch_bounds__(256) void build_kernel(
    const u16* __restrict__ qb, const u16* __restrict__ kb, u16* __restrict__ intA)
{
    __shared__ u16 sq[1024];
    __shared__ u16 sk[16][1024];
    int tid = threadIdx.x, blk = blockIdx.x;
    int b = blk >> 3, n0 = (blk & 7) * 16;
    for (int i = tid; i < 1024; i += 256) sq[i] = qb[b * 1024 + i];
    for (int j = tid; j < 16384; j += 256)
        sk[j >> 10][j & 1023] = kb[((size_t)(b * 128 + n0 + (j >> 10))) * 1024 + (j & 1023)];
    __syncthreads();
    for (int idx = tid; idx < 8192; idx += 256) {
        int n = idx >> 9, h = (idx >> 6) & 7, pi = idx & 63;
        int dd = pi * 2;                 // even d; pair (dd, dd+1)
        int hd = h * 128 + dd;
        unsigned qp = *(const unsigned*)&sq[hd];
        unsigned kp = *(const unsigned*)&sk[n][hd];
        float q0 = bf2f((u16)qp), q1 = bf2f((u16)(qp >> 16));
        float k0 = bf2f((u16)kp), k1 = bf2f((u16)(kp >> 16));
        float v0[4] = {q0, k0, fabsf(q0 - k0), q0 * k0};
        float v1[4] = {q1, k1, fabsf(q1 - k1), q1 * k1};
        int rowin = n * 8 + h;
        int p = KP(dd & 31);             // even; pair at p, p+1
        #pragma unroll
        for (int bt = 0; bt < 4; ++bt) {
            int kt = bt * 4 + (dd >> 5);
            size_t pos = ((size_t)(blk * 16 + kt) * 128 + rowin) * 32 + p;
            *(unsigned*)&intA[pos] = (unsigned)f2bf(v0[bt]) | ((unsigned)f2bf(v1[bt]) << 16);
        }
    }
}

#define MFMA(a, b, c) __builtin_amdgcn_mfma_f32_16x16x32_bf16(a, b, c, 0, 0, 0)

// ---------- kgemm: nf[8192x768] @ Wk[768x1024], gelu -> kbuf bf16 row-major
__global__ __launch_bounds__(512) void kgemm(
    const u16* __restrict__ gA, const u16* __restrict__ gB,
    const float* __restrict__ bias, u16* __restrict__ kbuf)
{
    __shared__ __attribute__((aligned(16))) u16 As[2][128 * 32];
    __shared__ __attribute__((aligned(16))) u16 Bs[2][256 * 32];
    const int tid = threadIdx.x, lane = tid & 63, w = tid >> 6;
    const int lr = lane & 15, g = lane >> 4;
    const int wr = w >> 2, wc = w & 3;
    const int nb = blockIdx.x, mb = blockIdx.y;   // 4 x 64
    const int NT = 24;
    f32x4 acc[4][4];
    #pragma unroll
    for (int i = 0; i < 4; ++i)
        #pragma unroll
        for (int j = 0; j < 4; ++j) acc[i][j] = (f32x4){0.f, 0.f, 0.f, 0.f};

    auto stage = [&](int t, int bi) {
        const u16* ab = gA + (size_t)(mb * 24 + t) * 4096;
        const u16* bb = gB + (size_t)(nb * 24 + t) * 8192;
        #pragma unroll
        for (int c = w; c < 24; c += 8) {
            if (c < 8) async_copy16(ab + c * 512 + lane * 8, &As[bi][c * 512]);
            else       async_copy16(bb + (c - 8) * 512 + lane * 8, &Bs[bi][(c - 8) * 512]);
        }
    };
    stage(0, 0);
    __syncthreads();
    for (int t = 0; t < NT; ++t) {
        int cur = t & 1;
        if (t + 1 < NT) stage(t + 1, cur ^ 1);
        s16x8 af[4], bf[4];
        #pragma unroll
        for (int i = 0; i < 4; ++i) af[i] = *(const s16x8*)&As[cur][(wr * 64 + i * 16 + lr) * 32 + g * 8];
        #pragma unroll
        for (int j = 0; j < 4; ++j) bf[j] = *(const s16x8*)&Bs[cur][(wc * 64 + j * 16 + lr) * 32 + g * 8];
        #pragma unroll
        for (int i = 0; i < 4; ++i)
            #pragma unroll
            for (int j = 0; j < 4; ++j) acc[i][j] = MFMA(af[i], bf[j], acc[i][j]);
        __syncthreads();
    }
    #pragma unroll
    for (int j = 0; j < 4; ++j) {
        int col = nb * 256 + wc * 64 + j * 16 + lr;
        float bv = bias[col];
        #pragma unroll
        for (int i = 0; i < 4; ++i) {
            #pragma unroll
            for (int r = 0; r < 4; ++r) {
                int row = mb * 128 + wr * 64 + i * 16 + 4 * g + r;
                kbuf[(size_t)row * 1024 + col] = f2bf(geluf(acc[i][j][r] + bv));
            }
        }
    }
}

// ---------- h1gemm: intA[65536x512] @ W1[512x256], gelu + LN -> h2A blocked bf16 [64][32] tiles
__global__ __launch_bounds__(512) void h1gemm(
    const u16* __restrict__ gA, const u16* __restrict__ gB,
    const float* __restrict__ b1, const float* __restrict__ g1,
    const float* __restrict__ bb1, u16* __restrict__ h2A)
{
    __shared__ __attribute__((aligned(16))) u16 As[2][128 * 32];
    __shared__ __attribute__((aligned(16))) u16 Bs[2][256 * 32];
    const int tid = threadIdx.x, lane = tid & 63, w = tid >> 6;
    const int lr = lane & 15, g = lane >> 4;
    const int wr = w >> 2, wc = w & 3;
    const int mb = blockIdx.x;   // 512
    const int NT = 16;
    f32x4 acc[4][4];
    #pragma unroll
    for (int i = 0; i < 4; ++i)
        #pragma unroll
        for (int j = 0; j < 4; ++j) acc[i][j] = (f32x4){0.f, 0.f, 0.f, 0.f};

    auto stage = [&](int t, int bi) {
        const u16* ab = gA + (size_t)(mb * 16 + t) * 4096;
        const u16* bb = gB + (size_t)t * 8192;
        #pragma unroll
        for (int c = w; c < 24; c += 8) {
            if (c < 8) async_copy16(ab + c * 512 + lane * 8, &As[bi][c * 512]);
            else       async_copy16(bb + (c - 8) * 512 + lane * 8, &Bs[bi][(c - 8) * 512]);
        }
    };
    stage(0, 0);
    __syncthreads();
    for (int t = 0; t < NT; ++t) {
        int cur = t & 1;
        if (t + 1 < NT) stage(t + 1, cur ^ 1);
        s16x8 af[4], bf[4];
        #pragma unroll
        for (int i = 0; i < 4; ++i) af[i] = *(const s16x8*)&As[cur][(wr * 64 + i * 16 + lr) * 32 + g * 8];
        #pragma unroll
        for (int j = 0; j < 4; ++j) bf[j] = *(const s16x8*)&Bs[cur][(wc * 64 + j * 16 + lr) * 32 + g * 8];
        #pragma unroll
        for (int i = 0; i < 4; ++i)
            #pragma unroll
            for (int j = 0; j < 4; ++j) acc[i][j] = MFMA(af[i], bf[j], acc[i][j]);
        __syncthreads();
    }
    // epilogue: gelu(+b1) in place, then LN over 256 cols, write h2A blocked
    #pragma unroll
    for (int j = 0; j < 4; ++j) {
        int col = wc * 64 + j * 16 + lr;
        float bv = b1[col];
        #pragma unroll
        for (int i = 0; i < 4; ++i) {
            f32x4 t = acc[i][j];
            #pragma unroll
            for (int r = 0; r < 4; ++r) t[r] = geluf(t[r] + bv);
            acc[i][j] = t;
        }
    }
    __syncthreads();
    float* part = (float*)&As[0][0];   // [128 rows][4 wc][2]
    float s1[4][4], s2[4][4];
    #pragma unroll
    for (int i = 0; i < 4; ++i)
        #pragma unroll
        for (int r = 0; r < 4; ++r) {
            float a = 0.f, b = 0.f;
            #pragma unroll
            for (int j = 0; j < 4; ++j) { float v = acc[i][j][r]; a += v; b += v * v; }
            #pragma unroll
            for (int m = 1; m <= 8; m <<= 1) { a += __shfl_xor(a, m, 64); b += __shfl_xor(b, m, 64); }
            s1[i][r] = a; s2[i][r] = b;
        }
    if (lr == 0) {
        #pragma unroll
        for (int i = 0; i < 4; ++i)
            #pragma unroll
            for (int r = 0; r < 4; ++r) {
                int rl = wr * 64 + i * 16 + 4 * g + r;
                part[(rl * 4 + wc) * 2 + 0] = s1[i][r];
                part[(rl * 4 + wc) * 2 + 1] = s2[i][r];
            }
    }
    __syncthreads();
    #pragma unroll
    for (int i = 0; i < 4; ++i) {
        #pragma unroll
        for (int r = 0; r < 4; ++r) {
            int rl = wr * 64 + i * 16 + 4 * g + r;
            float S = 0.f, S2 = 0.f;
            #pragma unroll
            for (int w4 = 0; w4 < 4; ++w4) { S += part[(rl * 4 + w4) * 2]; S2 += part[(rl * 4 + w4) * 2 + 1]; }
            float mu = S * (1.f / 256.f);
            float var = S2 * (1.f / 256.f) - mu * mu;
            float rs = rsqrtf(var + 1e-5f);
            int gr = mb * 128 + rl;
            size_t rb = (size_t)(gr >> 6) * 8;
            int rin = gr & 63;
            #pragma unroll
            for (int j = 0; j < 4; ++j) {
                int col = wc * 64 + j * 16 + lr;
                float ln = (acc[i][j][r] - mu) * rs * g1[col] + bb1[col];
                int kt = wc * 2 + (j >> 1);
                int kk = ((lr & 12) << 1) | ((j & 1) << 2) | (lr & 3);   // KP(col&31)
                h2A[((rb + kt) * 64 + rin) * 32 + kk] = f2bf(ln);
            }
        }
    }
}

// ---------- h2gemm: h2A[65536x256] @ W2[256x128], gelu + LN + dot(W3) -> scores f32
__global__ __launch_bounds__(256) void h2gemm(
    const u16* __restrict__ gA, const u16* __restrict__ gB,
    const float* __restrict__ b2, const float* __restrict__ g2,
    const float* __restrict__ bb2, const float* __restrict__ W3,
    const float* __restrict__ b3, float* __restrict__ scores)
{
    __shared__ __attribute__((aligned(16))) u16 As[2][64 * 32];
    __shared__ __attribute__((aligned(16))) u16 Bs[2][128 * 32];
    const int tid = threadIdx.x, lane = tid & 63, w = tid >> 6;
    const int lr = lane & 15, g = lane >> 4;
    const int wr = w >> 1, wc = w & 1;
    const int mb = blockIdx.x;   // 1024
    const int NT = 8;
    f32x4 acc[2][4];
    #pragma unroll
    for (int i = 0; i < 2; ++i)
        #pragma unroll
        for (int j = 0; j < 4; ++j) acc[i][j] = (f32x4){0.f, 0.f, 0.f, 0.f};

    auto stage = [&](int t, int bi) {
        const u16* ab = gA + (size_t)(mb * 8 + t) * 2048;
        const u16* bb = gB + (size_t)t * 4096;
        #pragma unroll
        for (int c = w; c < 12; c += 4) {
            if (c < 4) async_copy16(ab + c * 512 + lane * 8, &As[bi][c * 512]);
            else       async_copy16(bb + (c - 4) * 512 + lane * 8, &Bs[bi][(c - 4) * 512]);
        }
    };
    stage(0, 0);
    __syncthreads();
    for (int t = 0; t < NT; ++t) {
        int cur = t & 1;
        if (t + 1 < NT) stage(t + 1, cur ^ 1);
        s16x8 af[2], bf[4];
        #pragma unroll
        for (int i = 0; i < 2; ++i) af[i] = *(const s16x8*)&As[cur][(wr * 32 + i * 16 + lr) * 32 + g * 8];
        #pragma unroll
        for (int j = 0; j < 4; ++j) bf[j] = *(const s16x8*)&Bs[cur][(wc * 64 + j * 16 + lr) * 32 + g * 8];
        #pragma unroll
        for (int i = 0; i < 2; ++i)
            #pragma unroll
            for (int j = 0; j < 4; ++j) acc[i][j] = MFMA(af[i], bf[j], acc[i][j]);
        __syncthreads();
    }
    // epilogue: gelu(+b2), LN over 128, dot W3 -> scores
    #pragma unroll
    for (int j = 0; j < 4; ++j) {
        int col = wc * 64 + j * 16 + lr;
        float bv = b2[col];
        #pragma unroll
        for (int i = 0; i < 2; ++i) {
            f32x4 t = acc[i][j];
            #pragma unroll
            for (int r = 0; r < 4; ++r) t[r] = geluf(t[r] + bv);
            acc[i][j] = t;
        }
    }
    __syncthreads();
    float* part = (float*)&As[0][0];   // [64][2][2]
    float* dotb = part + 256;          // [64][2]
    #pragma unroll
    for (int i = 0; i < 2; ++i)
        #pragma unroll
        for (int r = 0; r < 4; ++r) {
            float a = 0.f, b = 0.f;
            #pragma unroll
            for (int j = 0; j < 4; ++j) { float v = acc[i][j][r]; a += v; b += v * v; }
            #pragma unroll
            for (int m = 1; m <= 8; m <<= 1) { a += __shfl_xor(a, m, 64); b += __shfl_xor(b, m, 64); }
            if (lr == 0) {
                int rl = wr * 32 + i * 16 + 4 * g + r;
                part[(rl * 2 + wc) * 2 + 0] = a;
                part[(rl * 2 + wc) * 2 + 1] = b;
            }
        }
    __syncthreads();
    #pragma unroll
    for (int i = 0; i < 2; ++i)
        #pragma unroll
        for (int r = 0; r < 4; ++r) {
            int rl = wr * 32 + i * 16 + 4 * g + r;
            float S = part[rl * 4] + part[rl * 4 + 2];
            float S2 = part[rl * 4 + 1] + part[rl * 4 + 3];
            float mu = S * (1.f / 128.f);
            float var = S2 * (1.f / 128.f) - mu * mu;
            float rs = rsqrtf(var + 1e-5f);
            float d = 0.f;
            #pragma unroll
            for (int j = 0; j < 4; ++j) {
                int col = wc * 64 + j * 16 + lr;
                float ln = (acc[i][j][r] - mu) * rs * g2[col] + bb2[col];
                d += ln * W3[col];
            }
            #pragma unroll
            for (int m = 1; m <= 8; m <<= 1) d += __shfl_xor(d, m, 64);
            if (lr == 0) dotb[rl * 2 + wc] = d;
        }
    __syncthreads();
    if (wc == 0 && lr == 0) {
        float b3v = b3[0];
        #pragma unroll
        for (int i = 0; i < 2; ++i)
            #pragma unroll
            for (int r = 0; r < 4; ++r) {
                int rl = wr * 32 + i * 16 + 4 * g + r;
                scores[mb * 64 + rl] = dotb[rl * 2] + dotb[rl * 2 + 1] + b3v;
            }
    }
}

// ---------- out[b] = sigmoid( sum_{n,h} score*gate*mask / 8 )
__global__ __launch_bounds__(256) void final_kernel(
    const float* __restrict__ scores, const float* __restrict__ idfs,
    const float* __restrict__ mask, const float* __restrict__ gate_w,
    const float* __restrict__ gate_b, float* __restrict__ outp)
{
    int b = blockIdx.x, tid = threadIdx.x;
    float gw = gate_w[0], gb = gate_b[0];
    float acc = 0.f;
    for (int i = tid; i < 1024; i += 256) {
        int n = i >> 3;
        float lg = log1pf(idfs[b * 128 + n]);
        float gate = 1.f / (1.f + expf(-(lg * gw + gb)));
        acc += scores[b * 1024 + i] * gate * mask[b * 128 + n];
    }
    acc = wave_reduce_sum(acc);
    __shared__ float wsum[4];
    if ((tid & 63) == 0) wsum[tid >> 6] = acc;
    __syncthreads();
    if (tid == 0) {
        float t = wsum[0] + wsum[1] + wsum[2] + wsum[3];
        outp[b] = 1.f / (1.f + expf(-t * 0.125f));
    }
}

extern "C" void kernel_launch(void* const* d_in, const int* in_sizes, int n_in,
                              void* d_out, int out_size, void* d_ws, size_t ws_size,
                              hipStream_t stream) {
    const float* q_emb    = (const float*)d_in[0];
    const float* ent      = (const float*)d_in[1];
    const int*   roles    = (const int*)d_in[2];
    const float* idfs     = (const float*)d_in[3];
    const float* mask     = (const float*)d_in[4];
    const float* role_emb = (const float*)d_in[5];
    const float* ln_f_g   = (const float*)d_in[6];
    const float* ln_f_b   = (const float*)d_in[7];
    const float* Wq       = (const float*)d_in[8];
    const float* bq       = (const float*)d_in[9];
    const float* Wk       = (const float*)d_in[10];
    const float* bk       = (const float*)d_in[11];
    const float* W1       = (const float*)d_in[12];
    const float* b1       = (const float*)d_in[13];
    const float* ln1_g    = (const float*)d_in[14];
    const float* ln1_b    = (const float*)d_in[15];
    const float* W2       = (const float*)d_in[16];
    const float* b2       = (const float*)d_in[17];
    const float* ln2_g    = (const float*)d_in[18];
    const float* ln2_b    = (const float*)d_in[19];
    const float* W3       = (const float*)d_in[20];
    const float* b3       = (const float*)d_in[21];
    const float* gate_w   = (const float*)d_in[22];
    const float* gate_b   = (const float*)d_in[23];
    float* outp = (float*)d_out;

    // workspace layout (bytes), overlapped live ranges; peak ~102.7 MB
    char* ws = (char*)d_ws;
    float* scores = (float*)(ws);                        // [65536] f32 (reuses dead intA head)
    u16* intA = (u16*)(ws);                              // 0 .. 67.1MB (65536x512)
    u16* nfb  = (u16*)(ws);                              // 0 .. 12.6MB (inside intA; dead before build)
    u16* kbuf = (u16*)(ws + (size_t)67108864);           // 16.8MB (dead after build)
    u16* h2A  = (u16*)(ws + (size_t)67108864);           // 33.6MB (reuses kbuf) .. 100.7MB
    u16* WkT  = (u16*)(ws + (size_t)100663296);          // 1.57MB
    u16* W1T  = (u16*)(ws + (size_t)102236160);          // 0.26MB
    u16* W2T  = (u16*)(ws + (size_t)102498304);          // 64KB
    u16* qbuf = (u16*)(ws + (size_t)102563840);          // 128KB .. 102.7MB

    prep_w<<<(768 * 1024 + 255) / 256, 256, 0, stream>>>(Wk, WkT, 768, 1024, 256);
    prep_w<<<(512 * 256 + 255) / 256, 256, 0, stream>>>(W1, W1T, 512, 256, 256);
    prep_w<<<(256 * 128 + 255) / 256, 256, 0, stream>>>(W2, W2T, 256, 128, 128);
    nf_ln_kernel<<<2048, 256, 0, stream>>>(ent, roles, role_emb, ln_f_g, ln_f_b, nfb);
    q_kernel<<<dim3(4, 64), 256, 0, stream>>>(q_emb, Wq, bq, qbuf);
    kgemm<<<dim3(4, 64), 512, 0, stream>>>(nfb, WkT, bk, kbuf);
    build_kernel<<<512, 256, 0, stream>>>(qbuf, kbuf, intA);
    h1gemm<<<512, 512, 0, stream>>>(intA, W1T, b1, ln1_g, ln1_b, h2A);
    h2gemm<<<1024, 256, 0, stream>>>(h2A, W2T, b2, ln2_g, ln2_b, W3, b3, scores);
    final_kernel<<<64, 256, 0, stream>>>(scores, idfs, mask, gate_w, gate_b, outp);
}